// Round 7
// baseline (215.470 us; speedup 1.0000x reference)
//
#include <hip/hip_runtime.h>
#include <float.h>
#include <stdint.h>

// SOM2D argmin ||x-w||^2 via split-f16 MFMA. N=32768, M=4096, D=128.
//
// score = ||w||^2 - 2 x.w  (||x||^2 constant per sample: dropped)
// cross = xh*wh + xl*wh + xh*wl  (f16 hi/lo split, fp32 accum; |err|~2e-5)
//
// Round-7:
//  (a) zero-cost software pipeline: bh regs are dead after pass 2 -> load
//      tile t+1's hi INTO THEM there; bl dead after pass 3 -> load t+1's lo
//      there. ~800/1300 cyc of cover vs ~300-500 cyc L2 latency, no extra
//      registers (peak ~220/wave, 2 waves/SIMD kept).
//  (b) finalize fused into main: per-sample-group atomic counter; the last
//      block of each group min-reduces the UG partial keys and writes labels.
//      2 dispatches total (prep, main).

constexpr int D = 128;

typedef _Float16 f16x8 __attribute__((ext_vector_type(8)));
typedef float    f32x4 __attribute__((ext_vector_type(4)));

__device__ __forceinline__ void cvt_split(const float4& a0, const float4& a1,
                                          f16x8& h, f16x8& l) {
    float v[8] = {a0.x, a0.y, a0.z, a0.w, a1.x, a1.y, a1.z, a1.w};
#pragma unroll
    for (int j = 0; j < 8; ++j) {
        _Float16 hh = (_Float16)v[j];
        h[j] = hh;
        l[j] = (_Float16)(v[j] - (float)hh);
    }
}

// W (M x D fp32) -> frag-major hi/lo f16 + wsq; also zeroes the group
// counters (ws is re-poisoned to 0xAA before every launch).
// Granule slot for (u, k=8o..8o+7), n-tile = 32 units:
//   T=u>>5, t=(u>>4)&1, c=u&15, s=o>>2, q=o&3
//   slot = T*512 + s*128 + t*64 + q*16 + c
// Main-loop read: tile_base(T*512) + s*128 + t*64 + lane. Sequential 1KB/instr.
__global__ __launch_bounds__(256) void prep_kernel(
        const float* __restrict__ w, f16x8* __restrict__ hG,
        f16x8* __restrict__ lG, float* __restrict__ wsq,
        int* __restrict__ cnt, int nGroups, int M) {
    if (cnt && blockIdx.x == 0 && (int)threadIdx.x < nGroups) cnt[threadIdx.x] = 0;
    int g = blockIdx.x * 256 + threadIdx.x;
    if (g >= M * 16) return;
    int u = g >> 4, o = g & 15;
    const float4* wp = reinterpret_cast<const float4*>(w + (size_t)u * D + o * 8);
    float4 a0 = wp[0], a1 = wp[1];
    f16x8 h, l;
    cvt_split(a0, a1, h, l);
    float ss = 0.f;
    ss = fmaf(a0.x, a0.x, ss); ss = fmaf(a0.y, a0.y, ss);
    ss = fmaf(a0.z, a0.z, ss); ss = fmaf(a0.w, a0.w, ss);
    ss = fmaf(a1.x, a1.x, ss); ss = fmaf(a1.y, a1.y, ss);
    ss = fmaf(a1.z, a1.z, ss); ss = fmaf(a1.w, a1.w, ss);
#pragma unroll
    for (int m = 1; m < 16; m <<= 1) ss += __shfl_xor(ss, m, 64);
    if (o == 0) wsq[u] = ss;
    int slot = ((u >> 5) << 9) + ((o >> 2) << 7) + (((u >> 4) & 1) << 6)
             + ((o & 3) << 4) + (u & 15);
    hG[slot] = h;
    lG[slot] = l;
}

template <bool PARTIAL>
__global__ __launch_bounds__(256, 2) void som_main(
        const float* __restrict__ x, const f16x8* __restrict__ hG,
        const f16x8* __restrict__ lG, const float* __restrict__ wsq,
        const int* __restrict__ grid, int* __restrict__ out,
        unsigned long long* __restrict__ keys, int* __restrict__ cnt,
        int unitGroups, int M, int N) {
    // Al (x-lo A-frags), wave-private: wave wv owns albuf[wv*1024 .. +1024)
    __shared__ f16x8 albuf[4 * 1024];   // 64 KB
    __shared__ int lastFlag;

    const int tid  = threadIdx.x;
    const int lane = tid & 63;
    const int wv   = tid >> 6;
    const int c    = lane & 15;   // frag col-class
    const int q    = lane >> 4;   // frag quad

    const int ug    = blockIdx.x % unitGroups;
    const int sg    = blockIdx.x / unitGroups;
    const int sWave = sg * 256 + wv * 64;   // this wave's 64 samples

    f16x8* myAl = &albuf[wv * 1024];

    // ---- A-frags: 64 samples x K=128. Ah resident (64 VGPRs); Al -> LDS.
    // A[m = lane&15][k = q*8 + j], m-tile i in 0..3, k-step s in 0..3.
    f16x8 Ah[16];
#pragma unroll
    for (int i = 0; i < 4; ++i) {
        const float* xr = x + (size_t)(sWave + 16 * i + c) * D + q * 8;
#pragma unroll
        for (int s = 0; s < 4; ++s) {
            float4 a0 = *reinterpret_cast<const float4*>(xr + 32 * s);
            float4 a1 = *reinterpret_cast<const float4*>(xr + 32 * s + 4);
            f16x8 h, l;
            cvt_split(a0, a1, h, l);
            Ah[i * 4 + s] = h;
            myAl[(i * 4 + s) * 64 + lane] = l;   // own slice only: no barrier
        }
    }

    float bestD[16];
    int   bestI[16];
#pragma unroll
    for (int sl = 0; sl < 16; ++sl) { bestD[sl] = FLT_MAX; bestI[sl] = 0; }

    const int tilesPer = (M / 32) / unitGroups;
    const int tile0    = ug * tilesPer;

    // ---- preload tile0's B (hi then lo) ----
    f16x8 bh[8], bl[8];
    {
        const f16x8* hp = hG + ((size_t)tile0 << 9) + lane;
        const f16x8* lp = lG + ((size_t)tile0 << 9) + lane;
#pragma unroll
        for (int s = 0; s < 4; ++s)
#pragma unroll
            for (int t = 0; t < 2; ++t) {
                bh[s * 2 + t] = hp[s * 128 + t * 64];
                bl[s * 2 + t] = lp[s * 128 + t * 64];
            }
    }

    for (int tt = 0; tt < tilesPer; ++tt) {
        const int tile  = tile0 + tt;
        const int tileN = (tt + 1 < tilesPer) ? tile + 1 : tile;  // clamped
        const f16x8* hpn = hG + ((size_t)tileN << 9) + lane;
        const f16x8* lpn = lG + ((size_t)tileN << 9) + lane;

        const int uTile = tile * 32;
        const float wq0 = wsq[uTile + c];        // issued early, used in scoring
        const float wq1 = wsq[uTile + 16 + c];

        f32x4 acc[8];   // [i*2 + t]
#pragma unroll
        for (int f = 0; f < 8; ++f) acc[f] = (f32x4){0.f, 0.f, 0.f, 0.f};

        // pass 1: xh.wh
#pragma unroll
        for (int s = 0; s < 4; ++s)
#pragma unroll
            for (int i = 0; i < 4; ++i)
#pragma unroll
                for (int t = 0; t < 2; ++t)
                    acc[i * 2 + t] = __builtin_amdgcn_mfma_f32_16x16x32_f16(
                        Ah[i * 4 + s], bh[s * 2 + t], acc[i * 2 + t], 0, 0, 0);
        // pass 2: xl.wh (Al from wave-private LDS)
#pragma unroll
        for (int s = 0; s < 4; ++s) {
            f16x8 al[4];
#pragma unroll
            for (int i = 0; i < 4; ++i) al[i] = myAl[(i * 4 + s) * 64 + lane];
#pragma unroll
            for (int i = 0; i < 4; ++i)
#pragma unroll
                for (int t = 0; t < 2; ++t)
                    acc[i * 2 + t] = __builtin_amdgcn_mfma_f32_16x16x32_f16(
                        al[i], bh[s * 2 + t], acc[i * 2 + t], 0, 0, 0);
        }
        // bh is now dead -> prefetch NEXT tile's hi into the same registers.
        // Cover: pass 3 + scoring (~800 cyc) >> L2 latency.
#pragma unroll
        for (int s = 0; s < 4; ++s)
#pragma unroll
            for (int t = 0; t < 2; ++t)
                bh[s * 2 + t] = hpn[s * 128 + t * 64];

        // pass 3: xh.wl
#pragma unroll
        for (int s = 0; s < 4; ++s)
#pragma unroll
            for (int i = 0; i < 4; ++i)
#pragma unroll
                for (int t = 0; t < 2; ++t)
                    acc[i * 2 + t] = __builtin_amdgcn_mfma_f32_16x16x32_f16(
                        Ah[i * 4 + s], bl[s * 2 + t], acc[i * 2 + t], 0, 0, 0);
        // bl dead -> prefetch NEXT tile's lo. Cover: scoring + next pass1+2.
#pragma unroll
        for (int s = 0; s < 4; ++s)
#pragma unroll
            for (int t = 0; t < 2; ++t)
                bl[s * 2 + t] = lpn[s * 128 + t * 64];

        // ---- score + per-lane argmin. C layout: row m = q*4+r (+16i), col = c (+16t).
#pragma unroll
        for (int t = 0; t < 2; ++t) {
            const int n    = uTile + 16 * t + c;
            const float wq = t == 0 ? wq0 : wq1;
#pragma unroll
            for (int i = 0; i < 4; ++i) {
                f32x4 a = acc[i * 2 + t];
#pragma unroll
                for (int r = 0; r < 4; ++r) {
                    float score = fmaf(-2.f, a[r], wq);
                    int sl = i * 4 + r;
                    if (score < bestD[sl]) { bestD[sl] = score; bestI[sl] = n; }
                }
            }
        }
    }

    // ---- reduce over the 16 col-classes (xor within each 16-lane q-group) ----
#pragma unroll
    for (int sl = 0; sl < 16; ++sl) {
        float d   = bestD[sl];
        int   idx = bestI[sl];
#pragma unroll
        for (int m = 1; m < 16; m <<= 1) {
            float od = __shfl_xor(d, m, 64);
            int   oi = __shfl_xor(idx, m, 64);
            if (od < d || (od == d && oi < idx)) { d = od; idx = oi; }
        }
        if (c == 0) {
            const int sOut = sWave + 16 * (sl >> 2) + 4 * q + (sl & 3);
            if (PARTIAL) {
                unsigned ub = __float_as_uint(d);
                ub = (ub & 0x80000000u) ? ~ub : (ub | 0x80000000u);  // monotone map
                unsigned long long key = ((unsigned long long)ub << 32) | (unsigned)idx;
                keys[(size_t)ug * N + sOut] = key;
            } else {
                out[2 * sOut]     = grid[2 * idx];
                out[2 * sOut + 1] = grid[2 * idx + 1];
            }
        }
    }

    // ---- fused finalize: last block of this sample-group reduces partials ----
    if (PARTIAL) {
        __threadfence();          // release: make this block's keys visible
        __syncthreads();          // all waves' keys written + fenced
        if (tid == 0) {
            int old = atomicAdd(&cnt[sg], 1);
            lastFlag = (old == unitGroups - 1);
        }
        __syncthreads();
        if (lastFlag) {
            __threadfence();      // acquire: see other blocks' keys
            const int s = sg * 256 + tid;
            unsigned long long k = keys[s];
            for (int g = 1; g < unitGroups; ++g) {
                unsigned long long kg = keys[(size_t)g * N + s];
                if (kg < k) k = kg;   // equal dist -> lower idx (smaller key)
            }
            const int idx = (int)(unsigned)(k & 0xFFFFFFFFull);
            out[2 * s]     = grid[2 * idx];
            out[2 * s + 1] = grid[2 * idx + 1];
        }
    }
}

extern "C" void kernel_launch(void* const* d_in, const int* in_sizes, int n_in,
                              void* d_out, int out_size, void* d_ws, size_t ws_size,
                              hipStream_t stream) {
    const float* x    = (const float*)d_in[0];
    const float* w    = (const float*)d_in[1];
    const int*   grid = (const int*)d_in[2];
    int* out = (int*)d_out;

    const int N = in_sizes[0] / D;   // 32768
    const int M = in_sizes[1] / D;   // 4096
    const int nGroups = N / 256;     // 128 sample-groups

    // ws layout: hG (1 MB) | lG (1 MB) | wsq (16 KB) | keys (UG*N*8) | cnt
    const size_t hlBytes   = (size_t)M * D * 2;
    const size_t baseBytes = 2 * hlBytes + (size_t)M * 4;

    f16x8* hG  = (f16x8*)d_ws;
    f16x8* lG  = (f16x8*)((char*)d_ws + hlBytes);
    float* wsq = (float*)((char*)d_ws + 2 * hlBytes);

    int UG = 0;
    if (ws_size >= baseBytes + 4ull * N * 8 + (size_t)nGroups * 4) UG = 4;
    else if (ws_size >= baseBytes + 2ull * N * 8 + (size_t)nGroups * 4) UG = 2;

    unsigned long long* keys = (unsigned long long*)((char*)d_ws + baseBytes);
    int* cnt = (int*)((char*)d_ws + baseBytes + (size_t)UG * N * 8);

    prep_kernel<<<(M * 16 + 255) / 256, 256, 0, stream>>>(
        w, hG, lG, wsq, UG > 0 ? cnt : nullptr, nGroups, M);

    if (UG > 0) {
        som_main<true><<<nGroups * UG, 256, 0, stream>>>(
            x, hG, lG, wsq, grid, out, keys, cnt, UG, M, N);
    } else {
        som_main<false><<<nGroups, 256, 0, stream>>>(
            x, hG, lG, wsq, grid, out, nullptr, nullptr, 1, M, N);
    }
}